// Round 1
// baseline (1314.825 us; speedup 1.0000x reference)
//
#include <hip/hip_runtime.h>
#include <hip/hip_fp16.h>

#define T_ 512
#define B_ 512
#define D_ 300
#define H_ 128
#define E_ 64
#define EGO_ 12
#define DH_ 428      // D_+H_
#define BD_ 153600   // B_*D_

typedef __attribute__((ext_vector_type(2))) _Float16 half2_t;

__device__ __forceinline__ float fdot2(unsigned a, unsigned b, float c) {
#if __has_builtin(__builtin_amdgcn_fdot2)
  return __builtin_amdgcn_fdot2(__builtin_bit_cast(half2_t, a),
                                __builtin_bit_cast(half2_t, b), c, false);
#else
  half2_t ha = __builtin_bit_cast(half2_t, a);
  half2_t hb = __builtin_bit_cast(half2_t, b);
  return c + (float)ha.x * (float)hb.x + (float)ha.y * (float)hb.y;
#endif
}

__device__ __forceinline__ unsigned pack2(float a, float b) {
  __half2 h = __floats2half2_rn(a, b);
  return __builtin_bit_cast(unsigned, h);
}

__device__ __forceinline__ float sigm(float x) {
  float e = __builtin_amdgcn_exp2f(-1.4426950408889634f * x);
  return __builtin_amdgcn_rcpf(1.0f + e);
}
__device__ __forceinline__ float tanh_(float x) {
  float e = __builtin_amdgcn_exp2f(2.8853900817779268f * x);
  return 1.0f - 2.0f * __builtin_amdgcn_rcpf(1.0f + e);
}

// ---------------- prefix sums of len_sequence -> ws ----------------
__global__ void prefix_k(const int* __restrict__ L, int* __restrict__ pfx) {
  __shared__ int s[T_];
  int t = threadIdx.x;
  s[t] = L[t];
  __syncthreads();
  for (int off = 1; off < T_; off <<= 1) {
    int v = 0;
    if (t >= off) v = s[t - off];
    __syncthreads();
    s[t] += v;
    __syncthreads();
  }
  if (t == 0) pfx[0] = 0;
  pfx[t + 1] = s[t];
}

// ---------------- LSTM scan, 2 batch rows per block, fused rnn-part of output
// thread tid owns gate row tid: [0:128)=i, [128:256)=f, [256:384)=g, [384:512)=o
__launch_bounds__(512, 2)
__global__ void scan_k(const float* __restrict__ state,
                       const float* __restrict__ h0,
                       const float* __restrict__ c0,
                       const int* __restrict__ lens,
                       const float* __restrict__ W_ih,
                       const float* __restrict__ W_hh,
                       const float* __restrict__ b_ih,
                       const float* __restrict__ b_hh,
                       const float* __restrict__ W_emb,
                       const float* __restrict__ b_emb,
                       const int* __restrict__ pfx,
                       float* __restrict__ out) {
  __shared__ __align__(16) unsigned h2[2][64];      // fp16x2 packed h per row
  __shared__ __align__(16) unsigned x2[2][2][8];    // [row][buf][dword]
  __shared__ float ai[2][128], ag[2][128], ao[2][128];
  __shared__ float part2[2][8][64];
  __shared__ int pfx_s[T_], len_s[T_];

  const int tid = threadIdx.x;
  const int b0 = blockIdx.x * 2;   // batch rows b0, b0+1

  // ---- weight-stationary registers (fp16 pairs)
  unsigned whh[64];
  {
    const float2* wr = (const float2*)(W_hh + tid * H_);
#pragma unroll
    for (int i = 0; i < 64; ++i) { float2 w = wr[i]; whh[i] = pack2(w.x, w.y); }
  }
  unsigned wih[6];
  {
    const float* xr = W_ih + tid * EGO_;
#pragma unroll
    for (int i = 0; i < 6; ++i) wih[i] = pack2(xr[2 * i], xr[2 * i + 1]);
  }
  const float bias = b_ih[tid] + b_hh[tid];
  const int e = tid & 63;
  const int q = tid >> 6;          // 0..7, wave index
  unsigned wemb[8];
  {
    const float* er = W_emb + e * DH_ + D_ + q * 16;
#pragma unroll
    for (int i = 0; i < 8; ++i) wemb[i] = pack2(er[2 * i], er[2 * i + 1]);
  }
  const float bemb = b_emb[e];

  // ---- LDS init
  pfx_s[tid] = pfx[tid];
  len_s[tid] = lens[tid];
  if (tid < 128) {
    int row = tid >> 6, i = tid & 63;
    const float2* hp = (const float2*)(h0 + (b0 + row) * H_);
    float2 v = hp[i];
    h2[row][i] = pack2(v.x, v.y);
  }
  float cs0 = 0.f, cs1 = 0.f;
  if (tid >= 128 && tid < 256) {
    int u = tid - 128;
    cs0 = c0[b0 * H_ + u];
    cs1 = c0[(b0 + 1) * H_ + u];
  }
  float2 xheld = make_float2(0.f, 0.f);
  if (tid < 12) {
    int row = tid / 6, j = tid % 6;
    const float2* xp0 = (const float2*)(state + (b0 + row) * D_);
    float2 v = xp0[j];
    x2[row][0][j] = pack2(v.x, v.y);
    const float2* xp1 = (const float2*)(state + BD_ + (b0 + row) * D_);
    xheld = xp1[j];   // x(t=1)
  }
  __syncthreads();

#pragma unroll 1
  for (int t = 0; t < T_; ++t) {
    // prefetch x(t+2) into regs (latency hidden by this step's compute)
    float2 xnew = xheld;
    if (tid < 12) {
      int row = tid / 6, j = tid % 6;
      int tt = (t + 2 < T_) ? t + 2 : T_ - 1;
      const float2* xp = (const float2*)(state + (size_t)tt * BD_ + (b0 + row) * D_);
      xnew = xp[j];
    }

    // ---- gates for both rows (dual accumulators per row for ILP)
    float ga0 = bias, ga1 = 0.f, gb0 = bias, gb1 = 0.f;
    {
      const uint4* hA = (const uint4*)h2[0];
      const uint4* hB = (const uint4*)h2[1];
#pragma unroll
      for (int kk = 0; kk < 8; ++kk) {
        uint4 va = hA[2 * kk], va2 = hA[2 * kk + 1];
        uint4 vb = hB[2 * kk], vb2 = hB[2 * kk + 1];
        ga0 = fdot2(whh[8 * kk + 0], va.x, ga0);  ga1 = fdot2(whh[8 * kk + 1], va.y, ga1);
        ga0 = fdot2(whh[8 * kk + 2], va.z, ga0);  ga1 = fdot2(whh[8 * kk + 3], va.w, ga1);
        ga0 = fdot2(whh[8 * kk + 4], va2.x, ga0); ga1 = fdot2(whh[8 * kk + 5], va2.y, ga1);
        ga0 = fdot2(whh[8 * kk + 6], va2.z, ga0); ga1 = fdot2(whh[8 * kk + 7], va2.w, ga1);
        gb0 = fdot2(whh[8 * kk + 0], vb.x, gb0);  gb1 = fdot2(whh[8 * kk + 1], vb.y, gb1);
        gb0 = fdot2(whh[8 * kk + 2], vb.z, gb0);  gb1 = fdot2(whh[8 * kk + 3], vb.w, gb1);
        gb0 = fdot2(whh[8 * kk + 4], vb2.x, gb0); gb1 = fdot2(whh[8 * kk + 5], vb2.y, gb1);
        gb0 = fdot2(whh[8 * kk + 6], vb2.z, gb0); gb1 = fdot2(whh[8 * kk + 7], vb2.w, gb1);
      }
      const uint4* xA = (const uint4*)x2[0][t & 1];
      uint4 xa0 = xA[0], xa1 = xA[1];
      ga0 = fdot2(wih[0], xa0.x, ga0); ga1 = fdot2(wih[1], xa0.y, ga1);
      ga0 = fdot2(wih[2], xa0.z, ga0); ga1 = fdot2(wih[3], xa0.w, ga1);
      ga0 = fdot2(wih[4], xa1.x, ga0); ga1 = fdot2(wih[5], xa1.y, ga1);
      const uint4* xB = (const uint4*)x2[1][t & 1];
      uint4 xb0 = xB[0], xb1 = xB[1];
      gb0 = fdot2(wih[0], xb0.x, gb0); gb1 = fdot2(wih[1], xb0.y, gb1);
      gb0 = fdot2(wih[2], xb0.z, gb0); gb1 = fdot2(wih[3], xb0.w, gb1);
      gb0 = fdot2(wih[4], xb1.x, gb0); gb1 = fdot2(wih[5], xb1.y, gb1);
    }
    const float gA = ga0 + ga1;
    const float gB = gb0 + gb1;

    // ---- activations split by gate class
    if (tid < 128) {
      ai[0][tid] = sigm(gA); ai[1][tid] = sigm(gB);
    } else if (tid >= 256 && tid < 384) {
      int u = tid - 256;
      ag[0][u] = tanh_(gA); ag[1][u] = tanh_(gB);
    } else if (tid >= 384) {
      int u = tid - 384;
      ao[0][u] = sigm(gA); ao[1][u] = sigm(gB);
    }
    __syncthreads();   // B: activations visible

    // ---- c/h update (f-gate threads own cell state)
    if (tid >= 128 && tid < 256) {
      int u = tid - 128;
      cs0 = sigm(gA) * cs0 + ai[0][u] * ag[0][u];
      cs1 = sigm(gB) * cs1 + ai[1][u] * ag[1][u];
      float hA = ao[0][u] * tanh_(cs0);
      float hB = ao[1][u] * tanh_(cs1);
      float hA2 = __shfl_xor(hA, 1);
      float hB2 = __shfl_xor(hB, 1);
      if (!(u & 1)) {
        h2[0][u >> 1] = pack2(hA, hA2);
        h2[1][u >> 1] = pack2(hB, hB2);
      }
    }
    // stage x(t+1) into the other buffer
    if (tid < 12) {
      int row = tid / 6, j = tid % 6;
      x2[row][(t + 1) & 1][j] = pack2(xheld.x, xheld.y);
      xheld = xnew;
    }

    // ---- fused rnn-part of output for rows with b < L[t] (block-uniform)
    const int Lt = len_s[t];
    const bool act0 = (b0 < Lt), act1 = (b0 + 1 < Lt);
    if (act0 | act1) {
      __syncthreads();   // C: h2 ready
      {
        const uint4* hpa = (const uint4*)(h2[0] + q * 8);
        uint4 u0 = hpa[0], u1 = hpa[1];
        float p = 0.f, p2 = 0.f;
        p = fdot2(wemb[0], u0.x, p); p2 = fdot2(wemb[1], u0.y, p2);
        p = fdot2(wemb[2], u0.z, p); p2 = fdot2(wemb[3], u0.w, p2);
        p = fdot2(wemb[4], u1.x, p); p2 = fdot2(wemb[5], u1.y, p2);
        p = fdot2(wemb[6], u1.z, p); p2 = fdot2(wemb[7], u1.w, p2);
        part2[0][q][e] = p + p2;
        const uint4* hpb = (const uint4*)(h2[1] + q * 8);
        uint4 v0 = hpb[0], v1 = hpb[1];
        float r = 0.f, r2 = 0.f;
        r = fdot2(wemb[0], v0.x, r); r2 = fdot2(wemb[1], v0.y, r2);
        r = fdot2(wemb[2], v0.z, r); r2 = fdot2(wemb[3], v0.w, r2);
        r = fdot2(wemb[4], v1.x, r); r2 = fdot2(wemb[5], v1.y, r2);
        r = fdot2(wemb[6], v1.z, r); r2 = fdot2(wemb[7], v1.w, r2);
        part2[1][q][e] = r + r2;
      }
      __syncthreads();   // D: partials ready
      if (tid < 128) {
        int row = tid >> 6;
        if (row == 0 ? act0 : act1) {
          int ee = tid & 63;
          float s = bemb;
#pragma unroll
          for (int qq = 0; qq < 8; ++qq) s += part2[row][qq][ee];
          out[(size_t)(pfx_s[t] + b0 + row) * E_ + ee] = s;
        }
      }
    }
    __syncthreads();   // A for next iteration
  }
}

// ---------------- state-part of output: out[r,:] += state[j,k,:300] @ W_emb[:, :300]^T
#define ROWS_ 16
__launch_bounds__(256, 2)
__global__ void emb_state_k(const float* __restrict__ state,
                            const float* __restrict__ W_emb,
                            const int* __restrict__ pfx,
                            float* __restrict__ out, int N) {
  __shared__ __align__(16) unsigned srow[ROWS_][160];  // fp16x2, 320 f (300 valid)
  __shared__ float part[ROWS_][8][64];
  __shared__ int rk[ROWS_], rj[ROWS_];

  const int tid = threadIdx.x;
  const int r0 = blockIdx.x * ROWS_;
  const int eh = tid & 31;        // e base (handles eh and eh+32)
  const int q = tid >> 5;         // d-chunk 0..7, 20 dwords (40 floats) each

  // per-thread W_emb slices (fp16 pairs), zero-padded past D_
  unsigned w0[20], w1[20];
  {
    const float* r0p = W_emb + eh * DH_;
    const float* r1p = W_emb + (eh + 32) * DH_;
#pragma unroll
    for (int i4 = 0; i4 < 10; ++i4) {
      int d = 40 * q + 4 * i4;
      float4 f0 = make_float4(0.f, 0.f, 0.f, 0.f);
      float4 f1 = make_float4(0.f, 0.f, 0.f, 0.f);
      if (d + 3 < D_) {
        f0 = *(const float4*)(r0p + d);
        f1 = *(const float4*)(r1p + d);
      }
      w0[2 * i4] = pack2(f0.x, f0.y); w0[2 * i4 + 1] = pack2(f0.z, f0.w);
      w1[2 * i4] = pack2(f1.x, f1.y); w1[2 * i4 + 1] = pack2(f1.z, f1.w);
    }
  }

  // decode packed row -> (k = segment, j = offset) via prefix binary search
  if (tid < ROWS_) {
    int r = r0 + tid;
    int k = -1, j = 0;
    if (r < N) {
      int lo = 0, hi = T_;
      while (hi - lo > 1) {
        int mid = (lo + hi) >> 1;
        if (pfx[mid] <= r) lo = mid; else hi = mid;
      }
      k = lo; j = r - pfx[lo];
    }
    rk[tid] = k; rj[tid] = j;
  }
  __syncthreads();

  // stage 16 state rows as fp16 pairs (coalesced float4 reads)
#pragma unroll 1
  for (int v = tid; v < ROWS_ * 80; v += 256) {
    int row = v / 80, c4 = v - row * 80;
    unsigned pa = 0u, pb = 0u;
    int k = rk[row];
    if (k >= 0 && c4 < 75) {
      const float4* sp = (const float4*)(state + ((size_t)rj[row] * B_ + k) * D_);
      float4 f = sp[c4];
      pa = pack2(f.x, f.y); pb = pack2(f.z, f.w);
    }
    srow[row][2 * c4] = pa; srow[row][2 * c4 + 1] = pb;
  }
  __syncthreads();

#pragma unroll 1
  for (int row = 0; row < ROWS_; ++row) {
    float a0 = 0.f, a1 = 0.f;
    const uint4* hp = (const uint4*)(&srow[row][q * 20]);
#pragma unroll
    for (int i = 0; i < 5; ++i) {
      uint4 hv = hp[i];
      a0 = fdot2(w0[4 * i + 0], hv.x, a0); a1 = fdot2(w1[4 * i + 0], hv.x, a1);
      a0 = fdot2(w0[4 * i + 1], hv.y, a0); a1 = fdot2(w1[4 * i + 1], hv.y, a1);
      a0 = fdot2(w0[4 * i + 2], hv.z, a0); a1 = fdot2(w1[4 * i + 2], hv.z, a1);
      a0 = fdot2(w0[4 * i + 3], hv.w, a0); a1 = fdot2(w1[4 * i + 3], hv.w, a1);
    }
    part[row][q][eh] = a0;
    part[row][q][eh + 32] = a1;
  }
  __syncthreads();

#pragma unroll 1
  for (int v = tid; v < ROWS_ * E_; v += 256) {
    int row = v >> 6, ee = v & 63;
    if (r0 + row < N) {
      float s = 0.f;
#pragma unroll
      for (int qq = 0; qq < 8; ++qq) s += part[row][qq][ee];
      out[(size_t)(r0 + row) * E_ + ee] += s;
    }
  }
}

extern "C" void kernel_launch(void* const* d_in, const int* in_sizes, int n_in,
                              void* d_out, int out_size, void* d_ws, size_t ws_size,
                              hipStream_t stream) {
  const float* state = (const float*)d_in[0];
  const float* h0    = (const float*)d_in[1];
  const float* c0    = (const float*)d_in[2];
  const int*   lens  = (const int*)d_in[3];
  const float* W_ih  = (const float*)d_in[4];
  const float* W_hh  = (const float*)d_in[5];
  const float* b_ih  = (const float*)d_in[6];
  const float* b_hh  = (const float*)d_in[7];
  const float* W_emb = (const float*)d_in[8];
  const float* b_emb = (const float*)d_in[9];
  float* out = (float*)d_out;
  int* pfx = (int*)d_ws;            // 513 ints
  const int N = out_size / E_;

  prefix_k<<<1, T_, 0, stream>>>(lens, pfx);
  scan_k<<<B_ / 2, 512, 0, stream>>>(state, h0, c0, lens, W_ih, W_hh, b_ih, b_hh,
                                     W_emb, b_emb, pfx, out);
  emb_state_k<<<(N + ROWS_ - 1) / ROWS_, 256, 0, stream>>>(state, W_emb, pfx, out, N);
}

// Round 3
// 917.713 us; speedup vs baseline: 1.4327x; 1.4327x over previous
//
#include <hip/hip_runtime.h>
#include <hip/hip_fp16.h>

#define T_ 512
#define B_ 512
#define D_ 300
#define H_ 128
#define E_ 64
#define EGO_ 12
#define DH_ 428      // D_+H_
#define BD_ 153600   // B_*D_

typedef __attribute__((ext_vector_type(2))) _Float16 half2_t;
typedef __attribute__((ext_vector_type(8))) _Float16 half8_t;
typedef __attribute__((ext_vector_type(4))) float float4_t;

__device__ __forceinline__ unsigned pack2(float a, float b) {
  __half2 h = __floats2half2_rn(a, b);
  return __builtin_bit_cast(unsigned, h);
}
__device__ __forceinline__ half8_t h8(uint4 u) {
  return __builtin_bit_cast(half8_t, u);
}
__device__ __forceinline__ float sigm(float x) {
  float e = __builtin_amdgcn_exp2f(-1.4426950408889634f * x);
  return __builtin_amdgcn_rcpf(1.0f + e);
}
__device__ __forceinline__ float tanh_(float x) {
  float e = __builtin_amdgcn_exp2f(2.8853900817779268f * x);
  return 1.0f - 2.0f * __builtin_amdgcn_rcpf(1.0f + e);
}

// ---------------- prefix sums of len_sequence -> ws ----------------
__global__ void prefix_k(const int* __restrict__ L, int* __restrict__ pfx) {
  __shared__ int s[T_];
  int t = threadIdx.x;
  s[t] = L[t];
  __syncthreads();
  for (int off = 1; off < T_; off <<= 1) {
    int v = 0;
    if (t >= off) v = s[t - off];
    __syncthreads();
    s[t] += v;
    __syncthreads();
  }
  if (t == 0) pfx[0] = 0;
  pfx[t + 1] = s[t];
}

// ---------------- LSTM scan v3 ----------------------------------------------
// 256 blocks x 256 threads (4 waves), 2 batch rows/block (M=16 padded w/ static
// zero rows). Wave w owns h-units u in [32w,32w+32) for ALL 4 gate classes:
// tile (c,p): gate g = c*128 + w*32 + 2*n16 + p  (p = parity). Lane (n16,quad)
// with quad==0 then holds i/f/g/o for u-pair (32w+2*n16, +1) x rows 0,1 in-lane
// -> c/h update needs no cross-lane/act exchange. h2 double-buffered -> ONE
// __syncthreads per step. A-frags loaded once serve epilogue(t-1) + gates(t).
#define WS_ 84   // dword stride per row: 336B (16B-aligned), uniform bank spread
__launch_bounds__(256, 1)
__global__ void scan_k(const float* __restrict__ state,
                       const float* __restrict__ h0,
                       const float* __restrict__ c0,
                       const int* __restrict__ lens,
                       const float* __restrict__ W_ih,
                       const float* __restrict__ W_hh,
                       const float* __restrict__ b_ih,
                       const float* __restrict__ b_hh,
                       const float* __restrict__ W_emb,
                       const float* __restrict__ b_emb,
                       const int* __restrict__ pfx,
                       float* __restrict__ out) {
  __shared__ __align__(16) unsigned hb[2][16][WS_];  // fp16x2; dw<64=h, 64..69=x, rest 0
  __shared__ int pfx_s[T_], len_s[T_];

  const int tid  = threadIdx.x;
  const int lane = tid & 63;
  const int w    = tid >> 6;
  const int n16  = lane & 15;
  const int quad = lane >> 4;
  const int b0   = blockIdx.x * 2;

  // ---- weight-stationary gate B-fragments: tile (c,p), 5 K-slices (K=160)
  uint4 bfr[4][2][5];
  float bias[4][2];
#pragma unroll
  for (int c = 0; c < 4; ++c) {
#pragma unroll
    for (int p = 0; p < 2; ++p) {
      const int g = c * 128 + w * 32 + 2 * n16 + p;
      bias[c][p] = b_ih[g] + b_hh[g];
#pragma unroll
      for (int s = 0; s < 5; ++s) {
        unsigned pk[4];
#pragma unroll
        for (int pp = 0; pp < 4; ++pp) {
          const int k0 = s * 32 + quad * 8 + 2 * pp;   // even
          float f0 = 0.f, f1 = 0.f;
          if (k0 < 128) { f0 = W_hh[g * H_ + k0]; f1 = W_hh[g * H_ + k0 + 1]; }
          else if (k0 < 140) {
            f0 = W_ih[g * EGO_ + (k0 - 128)];
            if (k0 + 1 < 140) f1 = W_ih[g * EGO_ + (k0 - 127)];
          }
          pk[pp] = pack2(f0, f1);
        }
        bfr[c][p][s] = make_uint4(pk[0], pk[1], pk[2], pk[3]);
      }
    }
  }
  // ---- epilogue B-fragments (rnn half of W_emb), e = w*16+n16
  uint4 efr[4];
  const int e_ = w * 16 + n16;
  const float bemb = b_emb[e_];
#pragma unroll
  for (int s = 0; s < 4; ++s) {
    unsigned pk[4];
#pragma unroll
    for (int pp = 0; pp < 4; ++pp) {
      const int k0 = s * 32 + quad * 8 + 2 * pp;
      pk[pp] = pack2(W_emb[e_ * DH_ + D_ + k0], W_emb[e_ * DH_ + D_ + k0 + 1]);
    }
    efr[s] = make_uint4(pk[0], pk[1], pk[2], pk[3]);
  }

  // ---- LDS init: zero both buffers fully, then fill buf0 rows 0,1
  for (int i = tid; i < 2 * 16 * WS_; i += 256) ((unsigned*)hb)[i] = 0u;
  for (int i = tid; i < T_; i += 256) { pfx_s[i] = pfx[i]; len_s[i] = lens[i]; }
  __syncthreads();
  if (tid < 128) {
    const int r = tid >> 6, d = tid & 63;
    float2 v = ((const float2*)(h0 + (b0 + r) * H_))[d];
    hb[0][r][d] = pack2(v.x, v.y);
  }
  float2 xheld = make_float2(0.f, 0.f);
  if (tid >= 16 && tid < 28) {   // wave0/quad1 lanes do x staging
    const int j = tid - 16, row = j / 6, jj = j % 6;
    float2 v = ((const float2*)(state + (b0 + row) * D_))[jj];
    hb[0][row][64 + jj] = pack2(v.x, v.y);
    xheld = ((const float2*)(state + BD_ + (b0 + row) * D_))[jj];
  }
  float cst[2][2] = {{0.f, 0.f}, {0.f, 0.f}};
  if (quad == 0) {
#pragma unroll
    for (int r = 0; r < 2; ++r)
#pragma unroll
      for (int p = 0; p < 2; ++p)
        cst[r][p] = c0[(b0 + r) * H_ + w * 32 + 2 * n16 + p];
  }
  __syncthreads();

#pragma unroll 1
  for (int t = 0; t < T_; ++t) {
    const int pb = t & 1;
    // prefetch x(t+2)
    float2 xnew = xheld;
    if (tid >= 16 && tid < 28) {
      const int j = tid - 16, row = j / 6, jj = j % 6;
      const int ttx = (t + 2 < T_) ? t + 2 : T_ - 1;
      xnew = ((const float2*)(state + (size_t)ttx * BD_ + (b0 + row) * D_))[jj];
    }

    // ---- A-fragments from current buffer (h(t-1) | x(t) | 0)
    uint4 a[5];
#pragma unroll
    for (int s = 0; s < 5; ++s)
      a[s] = *(const uint4*)(&hb[pb][n16][s * 16 + quad * 4]);

    // ---- epilogue for t-1 (rnn-part of output row pfx[t-1]+b), uses h(t-1)
    if (t > 0) {
      float4_t ea = (float4_t){0.f, 0.f, 0.f, 0.f};
#pragma unroll
      for (int s = 0; s < 4; ++s)
        ea = __builtin_amdgcn_mfma_f32_16x16x32_f16(h8(a[s]), h8(efr[s]), ea, 0, 0, 0);
      if (quad == 0) {
        const int Lt = len_s[t - 1];
        const size_t base = (size_t)pfx_s[t - 1] + b0;
        if (b0 < Lt)     out[base * E_ + e_]       = ea[0] + bemb;
        if (b0 + 1 < Lt) out[(base + 1) * E_ + e_] = ea[1] + bemb;
      }
    }

    // ---- gates(t)
    float4_t acc[4][2];
#pragma unroll
    for (int c = 0; c < 4; ++c)
#pragma unroll
      for (int p = 0; p < 2; ++p) acc[c][p] = (float4_t){0.f, 0.f, 0.f, 0.f};
#pragma unroll
    for (int s = 0; s < 5; ++s) {
      const half8_t ah = h8(a[s]);
#pragma unroll
      for (int c = 0; c < 4; ++c)
#pragma unroll
        for (int p = 0; p < 2; ++p)
          acc[c][p] = __builtin_amdgcn_mfma_f32_16x16x32_f16(ah, h8(bfr[c][p][s]), acc[c][p], 0, 0, 0);
    }

    // ---- in-lane c/h update (quad==0 lanes own rows 0,1 = regs 0,1)
    if (quad == 0) {
#pragma unroll
      for (int r = 0; r < 2; ++r) {
        float hp[2];
#pragma unroll
        for (int p = 0; p < 2; ++p) {
          const float gi = acc[0][p][r] + bias[0][p];
          const float gf = acc[1][p][r] + bias[1][p];
          const float gg = acc[2][p][r] + bias[2][p];
          const float go = acc[3][p][r] + bias[3][p];
          const float cc = sigm(gf) * cst[r][p] + sigm(gi) * tanh_(gg);
          cst[r][p] = cc;
          hp[p] = sigm(go) * tanh_(cc);
        }
        hb[1 - pb][r][w * 16 + n16] = pack2(hp[0], hp[1]);
      }
    }
    // stage x(t+1) into next buffer
    if (tid >= 16 && tid < 28) {
      const int j = tid - 16, row = j / 6, jj = j % 6;
      hb[1 - pb][row][64 + jj] = pack2(xheld.x, xheld.y);
      xheld = xnew;
    }
    __syncthreads();   // writes to buf 1-pb visible; all reads of buf pb done
  }

  // ---- final epilogue for t = T-1 (h(511) lives in buffer T_&1 == 0)
  {
    float4_t ea = (float4_t){0.f, 0.f, 0.f, 0.f};
#pragma unroll
    for (int s = 0; s < 4; ++s) {
      uint4 a = *(const uint4*)(&hb[0][n16][s * 16 + quad * 4]);
      ea = __builtin_amdgcn_mfma_f32_16x16x32_f16(h8(a), h8(efr[s]), ea, 0, 0, 0);
    }
    if (quad == 0) {
      const int Lt = len_s[T_ - 1];
      const size_t base = (size_t)pfx_s[T_ - 1] + b0;
      if (b0 < Lt)     out[base * E_ + e_]       = ea[0] + bemb;
      if (b0 + 1 < Lt) out[(base + 1) * E_ + e_] = ea[1] + bemb;
    }
  }
}

// ---------------- state-part of output (MFMA): out[r,:] += state[j,b,:] @ W_emb[:,:300]^T
#define ER_ 16
#define ES_ 164   // dword stride: 656B (16B-aligned), uniform bank spread
__launch_bounds__(256, 4)
__global__ void emb_state_k(const float* __restrict__ state,
                            const float* __restrict__ W_emb,
                            const int* __restrict__ pfx,
                            float* __restrict__ out, int N) {
  __shared__ __align__(16) unsigned srow[ER_][ES_];  // fp16x2; k<300 data, rest 0
  __shared__ int rk[ER_], rj[ER_];

  const int tid  = threadIdx.x;
  const int lane = tid & 63;
  const int w    = tid >> 6;
  const int n16  = lane & 15;
  const int quad = lane >> 4;
  const int r0   = blockIdx.x * ER_;

  // ---- B-fragments: 10 K-slices of W_emb state-part, e = w*16+n16
  uint4 efr[10];
  const int e_ = w * 16 + n16;
#pragma unroll
  for (int s = 0; s < 10; ++s) {
    unsigned pk[4];
#pragma unroll
    for (int pp = 0; pp < 4; ++pp) {
      const int k0 = s * 32 + quad * 8 + 2 * pp;   // even
      float f0 = 0.f, f1 = 0.f;
      if (k0 < D_) {
        f0 = W_emb[e_ * DH_ + k0];
        if (k0 + 1 < D_) f1 = W_emb[e_ * DH_ + k0 + 1];
      }
      pk[pp] = pack2(f0, f1);
    }
    efr[s] = make_uint4(pk[0], pk[1], pk[2], pk[3]);
  }

  // ---- decode packed row r -> (segment b, offset j) via prefix binary search
  if (tid < ER_) {
    int r = r0 + tid;
    int k = -1, j = 0;
    if (r < N) {
      int lo = 0, hi = T_;
      while (hi - lo > 1) {
        int mid = (lo + hi) >> 1;
        if (pfx[mid] <= r) lo = mid; else hi = mid;
      }
      k = lo; j = r - pfx[lo];
    }
    rk[tid] = k; rj[tid] = j;
  }
  __syncthreads();

  // ---- stage 16 state rows as fp16 pairs (16 threads per row, coalesced)
  {
    const int row = tid >> 4, i = tid & 15;
    const int k = rk[row];
    const float4* sp = (const float4*)(state + ((size_t)rj[row] * B_ + (k < 0 ? 0 : k)) * D_);
#pragma unroll 1
    for (int c4 = i; c4 < 82; c4 += 16) {
      unsigned p0 = 0u, p1 = 0u;
      if (k >= 0 && c4 < 75) {
        float4 f = sp[c4];
        p0 = pack2(f.x, f.y); p1 = pack2(f.z, f.w);
      }
      srow[row][2 * c4] = p0;
      srow[row][2 * c4 + 1] = p1;
    }
  }
  __syncthreads();

  // ---- 10 MFMAs: D[row][e] += S @ W^T
  float4_t acc = (float4_t){0.f, 0.f, 0.f, 0.f};
#pragma unroll
  for (int s = 0; s < 10; ++s) {
    uint4 a = *(const uint4*)(&srow[n16][s * 16 + quad * 4]);
    acc = __builtin_amdgcn_mfma_f32_16x16x32_f16(h8(a), h8(efr[s]), acc, 0, 0, 0);
  }
#pragma unroll
  for (int r = 0; r < 4; ++r) {
    const int R = r0 + quad * 4 + r;
    if (R < N) out[(size_t)R * E_ + e_] += acc[r];
  }
}

extern "C" void kernel_launch(void* const* d_in, const int* in_sizes, int n_in,
                              void* d_out, int out_size, void* d_ws, size_t ws_size,
                              hipStream_t stream) {
  const float* state = (const float*)d_in[0];
  const float* h0    = (const float*)d_in[1];
  const float* c0    = (const float*)d_in[2];
  const int*   lens  = (const int*)d_in[3];
  const float* W_ih  = (const float*)d_in[4];
  const float* W_hh  = (const float*)d_in[5];
  const float* b_ih  = (const float*)d_in[6];
  const float* b_hh  = (const float*)d_in[7];
  const float* W_emb = (const float*)d_in[8];
  const float* b_emb = (const float*)d_in[9];
  float* out = (float*)d_out;
  int* pfx = (int*)d_ws;            // 513 ints
  const int N = out_size / E_;

  prefix_k<<<1, T_, 0, stream>>>(lens, pfx);
  scan_k<<<B_ / 2, 256, 0, stream>>>(state, h0, c0, lens, W_ih, W_hh, b_ih, b_hh,
                                     W_emb, b_emb, pfx, out);
  emb_state_k<<<(N + ER_ - 1) / ER_, 256, 0, stream>>>(state, W_emb, pfx, out, N);
}